// Round 1
// baseline (1605.657 us; speedup 1.0000x reference)
//
#include <hip/hip_runtime.h>

#define TT 96
#define DM 64
#define DI 128
#define NSTATE 16
#define NN 325
#define NBATCH 16

__global__ __launch_bounds__(512, 1)
void mamba_fused(const float* __restrict__ x,
                 const float* __restrict__ W_in,
                 const float* __restrict__ conv_w,
                 const float* __restrict__ conv_b,
                 const float* __restrict__ W_x,
                 const float* __restrict__ W_dt,
                 const float* __restrict__ b_dt,
                 const float* __restrict__ A_log,
                 const float* __restrict__ D_skip,
                 const float* __restrict__ W_out,
                 float* __restrict__ out)
{
    __shared__ __align__(16) float xw[TT * DI];    // xi, then xc (in-place conv)
    __shared__ __align__(16) float zbuf[TT * DI];  // z, then y_final
    __shared__ __align__(16) float xls[TT * DM];   // x staging; first TT*36 reused as dbl
    __shared__ __align__(16) float wxT[36 * DI];   // W_x transposed [j][c]

    const int tid = threadIdx.x;
    const int seq = blockIdx.x;
    const int b = seq / NN;
    const int n = seq - b * NN;
    const size_t trow = (size_t)NN * DM;                 // stride between timesteps
    const size_t gbase = ((size_t)b * TT * NN + n) * DM; // offset of (b, 0, n, 0)

    // ---- stage W_x transposed into LDS ----
    for (int idx = tid; idx < 36 * DI; idx += 512) {
        int j = idx >> 7;   // 0..35
        int c = idx & 127;
        wxT[idx] = W_x[c * 36 + j];
    }
    // ---- stage x rows into LDS ----
    {
        const int col = tid & 63;
        const int r0 = tid >> 6;  // 0..7
        for (int i = 0; i < TT / 8; ++i) {
            int t = r0 + i * 8;
            xls[t * DM + col] = x[gbase + (size_t)t * trow + col];
        }
    }
    __syncthreads();

    // ---- phase A: xz = x @ W_in ; columns 0..127 -> xw (xi), 128..255 -> zbuf (z) ----
    {
        const int c0 = (tid & 63) * 4;   // output column quad
        const int tg = tid >> 6;         // 0..7, t = tg + 8*i
        float acc[12][4];
        #pragma unroll
        for (int i = 0; i < 12; ++i) { acc[i][0]=0.f; acc[i][1]=0.f; acc[i][2]=0.f; acc[i][3]=0.f; }
        for (int k4 = 0; k4 < DM; k4 += 4) {
            float4 w0 = *(const float4*)&W_in[(k4 + 0) * 2 * DI + c0];
            float4 w1 = *(const float4*)&W_in[(k4 + 1) * 2 * DI + c0];
            float4 w2 = *(const float4*)&W_in[(k4 + 2) * 2 * DI + c0];
            float4 w3 = *(const float4*)&W_in[(k4 + 3) * 2 * DI + c0];
            #pragma unroll
            for (int i = 0; i < 12; ++i) {
                float4 a = *(const float4*)&xls[(tg + 8 * i) * DM + k4];
                acc[i][0] += a.x * w0.x + a.y * w1.x + a.z * w2.x + a.w * w3.x;
                acc[i][1] += a.x * w0.y + a.y * w1.y + a.z * w2.y + a.w * w3.y;
                acc[i][2] += a.x * w0.z + a.y * w1.z + a.z * w2.z + a.w * w3.z;
                acc[i][3] += a.x * w0.w + a.y * w1.w + a.z * w2.w + a.w * w3.w;
            }
        }
        #pragma unroll
        for (int i = 0; i < 12; ++i) {
            int t = tg + 8 * i;
            float4 v = make_float4(acc[i][0], acc[i][1], acc[i][2], acc[i][3]);
            if (c0 < DI) *(float4*)&xw[t * DI + c0] = v;
            else         *(float4*)&zbuf[t * DI + (c0 - DI)] = v;
        }
    }
    __syncthreads();

    // ---- causal conv4 + bias + SiLU, in-place on xw, descending 32-t chunks ----
    {
        const int c = tid & 127;
        const int tq = tid >> 7;  // 0..3
        const float4 cw = *(const float4*)&conv_w[c * 4];
        const float cb = conv_b[c];
        for (int chunk = 2; chunk >= 0; --chunk) {
            const int tb = chunk * 32;
            float v[8];
            #pragma unroll
            for (int i = 0; i < 8; ++i) {
                int t = tb + tq + 4 * i;
                float s = cb + xw[t * DI + c] * cw.w;
                if (t - 1 >= 0) s += xw[(t - 1) * DI + c] * cw.z;
                if (t - 2 >= 0) s += xw[(t - 2) * DI + c] * cw.y;
                if (t - 3 >= 0) s += xw[(t - 3) * DI + c] * cw.x;
                v[i] = s / (1.f + __expf(-s));   // silu
            }
            __syncthreads();
            #pragma unroll
            for (int i = 0; i < 8; ++i) {
                int t = tb + tq + 4 * i;
                xw[t * DI + c] = v[i];
            }
            __syncthreads();
        }
    }

    // ---- dbl = xc @ W_x  -> xls[t*36 + j]  (dt_r | B | C) ----
    {
        const int t = tid >> 2;    // 0..127 (guard <96)
        const int jl = tid & 3;
        if (t < TT) {
            float acc[9];
            #pragma unroll
            for (int i = 0; i < 9; ++i) acc[i] = 0.f;
            for (int cc = 0; cc < 32; ++cc) {
                const int c4 = ((cc + t) & 31) * 4;       // rotate to spread banks
                float4 xv = *(const float4*)&xw[t * DI + c4];
                #pragma unroll
                for (int i = 0; i < 9; ++i) {
                    float4 w4 = *(const float4*)&wxT[(jl + 4 * i) * DI + c4];
                    acc[i] += xv.x * w4.x + xv.y * w4.y + xv.z * w4.z + xv.w * w4.w;
                }
            }
            #pragma unroll
            for (int i = 0; i < 9; ++i)
                xls[t * 36 + jl + 4 * i] = acc[i];
        }
    }
    __syncthreads();

    // ---- sequential scan over t (barrier-free; 4 lanes per channel d) ----
    {
        const int d = tid >> 2;
        const int q = tid & 3;
        const int s0 = q * 4;
        const float w0 = W_dt[0 * DI + d], w1 = W_dt[1 * DI + d];
        const float w2 = W_dt[2 * DI + d], w3 = W_dt[3 * DI + d];
        const float bd = b_dt[d];
        const float4 al = *(const float4*)&A_log[d * NSTATE + s0];
        const float A0 = -__expf(al.x), A1 = -__expf(al.y);
        const float A2 = -__expf(al.z), A3 = -__expf(al.w);
        const float dsk = D_skip[d];
        float h0 = 0.f, h1 = 0.f, h2 = 0.f, h3 = 0.f;
        for (int t = 0; t < TT; ++t) {
            const float* db = &xls[t * 36];
            float4 dtr = *(const float4*)&db[0];
            float4 Bv  = *(const float4*)&db[4 + s0];
            float4 Cv  = *(const float4*)&db[20 + s0];
            float xc = xw[t * DI + d];
            float zv = zbuf[t * DI + d];
            float pre = bd + dtr.x * w0 + dtr.y * w1 + dtr.z * w2 + dtr.w * w3;
            float dt = (pre > 15.f) ? pre : __logf(1.f + __expf(pre));  // softplus
            float dx = dt * xc;
            h0 = __expf(dt * A0) * h0 + dx * Bv.x;
            h1 = __expf(dt * A1) * h1 + dx * Bv.y;
            h2 = __expf(dt * A2) * h2 + dx * Bv.z;
            h3 = __expf(dt * A3) * h3 + dx * Bv.w;
            float y = h0 * Cv.x + h1 * Cv.y + h2 * Cv.z + h3 * Cv.w;
            y += __shfl_xor(y, 1);
            y += __shfl_xor(y, 2);
            if (q == 0) {
                float yf = (y + xc * dsk) * (zv / (1.f + __expf(-zv)));  // * silu(z)
                zbuf[t * DI + d] = yf;
            }
        }
    }
    __syncthreads();

    // ---- phase C: out = y_final @ W_out ----
    {
        const int o0 = (tid & 15) * 4;  // output dim quad
        const int tg = tid >> 4;        // 0..31, t = tg + 32*i
        float acc[3][4];
        #pragma unroll
        for (int i = 0; i < 3; ++i) { acc[i][0]=0.f; acc[i][1]=0.f; acc[i][2]=0.f; acc[i][3]=0.f; }
        for (int cc = 0; cc < 32; ++cc) {
            float4 w0 = *(const float4*)&W_out[(cc * 4 + 0) * DM + o0];
            float4 w1 = *(const float4*)&W_out[(cc * 4 + 1) * DM + o0];
            float4 w2 = *(const float4*)&W_out[(cc * 4 + 2) * DM + o0];
            float4 w3 = *(const float4*)&W_out[(cc * 4 + 3) * DM + o0];
            #pragma unroll
            for (int i = 0; i < 3; ++i) {
                float4 y4 = *(const float4*)&zbuf[(tg + 32 * i) * DI + cc * 4];
                acc[i][0] += y4.x * w0.x + y4.y * w1.x + y4.z * w2.x + y4.w * w3.x;
                acc[i][1] += y4.x * w0.y + y4.y * w1.y + y4.z * w2.y + y4.w * w3.y;
                acc[i][2] += y4.x * w0.z + y4.y * w1.z + y4.z * w2.z + y4.w * w3.z;
                acc[i][3] += y4.x * w0.w + y4.y * w1.w + y4.z * w2.w + y4.w * w3.w;
            }
        }
        #pragma unroll
        for (int i = 0; i < 3; ++i) {
            int t = tg + 32 * i;
            *(float4*)&out[gbase + (size_t)t * trow + o0] =
                make_float4(acc[i][0], acc[i][1], acc[i][2], acc[i][3]);
        }
    }
}

extern "C" void kernel_launch(void* const* d_in, const int* in_sizes, int n_in,
                              void* d_out, int out_size, void* d_ws, size_t ws_size,
                              hipStream_t stream) {
    const float* x      = (const float*)d_in[0];
    const float* W_in   = (const float*)d_in[1];
    const float* conv_w = (const float*)d_in[2];
    const float* conv_b = (const float*)d_in[3];
    const float* W_x    = (const float*)d_in[4];
    const float* W_dt   = (const float*)d_in[5];
    const float* b_dt   = (const float*)d_in[6];
    const float* A_log  = (const float*)d_in[7];
    const float* D_skip = (const float*)d_in[8];
    const float* W_out  = (const float*)d_in[9];
    float* outp = (float*)d_out;

    dim3 grid(NBATCH * NN);  // 5200 sequences
    mamba_fused<<<grid, 512, 0, stream>>>(x, W_in, conv_w, conv_b, W_x, W_dt,
                                          b_dt, A_log, D_skip, W_out, outp);
}